// Round 6
// baseline (920.309 us; speedup 1.0000x reference)
//
#include <hip/hip_runtime.h>
#include <hip/hip_bf16.h>

#define Bn   32
#define Sn   2048
#define Dn   768
#define QDn  256
#define OUTn 1024

typedef __attribute__((ext_vector_type(8))) short          bf16x8;
typedef __attribute__((ext_vector_type(4))) float          f32x4;
typedef __attribute__((ext_vector_type(8))) unsigned short u16x8;
typedef __attribute__((ext_vector_type(4))) unsigned short u16x4;

typedef unsigned short ushort_t;

__device__ __forceinline__ unsigned short f2bf(float f) {
    unsigned int u = __float_as_uint(f);
    u = (u + 0x7FFFu + ((u >> 16) & 1u)) >> 16;   // RNE
    return (unsigned short)u;
}
#define MFMA16(a,b,c) __builtin_amdgcn_mfma_f32_16x16x32_bf16((a),(b),(c),0,0,0)

// ---------------------------------------------------------------------------
// wconv: one-time fp32 -> bf16 of W1/W2 (pure-bf16 pipeline: no lo terms).
// ---------------------------------------------------------------------------
__global__ __launch_bounds__(256) void wconv_kernel(
    const float* __restrict__ W1, const float* __restrict__ W2,
    ushort_t* __restrict__ W1h, ushort_t* __restrict__ W2h)
{
    const int idx = blockIdx.x * 256 + threadIdx.x;   // grid 768 -> 196608
    W1h[idx] = f2bf(W1[idx]);
    W2h[idx] = f2bf(W2[idx]);
}

// ---------------------------------------------------------------------------
// proj: [Q|K] = data @ W^T + b, pure bf16 MFMA.  (round-2 verified form;
// dconv/Db experiment reverted: net-negative, polluted L3 during attn)
// grid (2 halves, 512 m-tiles), 256 thr = 4 waves, tile 128m x 256n.
// ---------------------------------------------------------------------------
__global__ __launch_bounds__(256, 2) void proj_kernel(
    const float* __restrict__ data,
    const ushort_t* __restrict__ W1h, const float* __restrict__ b1,
    const ushort_t* __restrict__ W2h, const float* __restrict__ b2,
    ushort_t* __restrict__ Qb, ushort_t* __restrict__ Kb,
    ushort_t* __restrict__ KTb)
{
    __shared__ __align__(16) char smem[34816];
    ushort_t* DH = (ushort_t*)smem;              // data bf16 [128][40]
    ushort_t* WH = (ushort_t*)(smem + 10240);    // W bf16 [256][40]
    ushort_t* EP = (ushort_t*)smem;              // epilogue overlay

    const int tid  = threadIdx.x;
    const int w    = tid >> 6;
    const int quad = (tid >> 4) & 3;
    const int n15  = tid & 15;
    const int mtile = blockIdx.y;
    const int half  = blockIdx.x;
    const bool isQ  = (half == 0);
    const ushort_t* WhP = isQ ? W1h : W2h;
    const float* bp = isQ ? b1 : b2;

    f32x4 acc[2][16];
    #pragma unroll
    for (int i = 0; i < 2; ++i)
        #pragma unroll
        for (int j = 0; j < 16; ++j) acc[i][j] = (f32x4)0.f;

    const size_t drow = (size_t)mtile * 128;

    for (int kt = 0; kt < 24; ++kt) {
        const int kc = kt * 32;
        // stage data chunk [128 m][32 k] fp32 -> bf16
        {
            const int m  = tid >> 1;
            const int k0 = (tid & 1) << 4;
            const float* src = data + (drow + m) * 768 + kc + k0;
            const float4 v0 = *(const float4*)(src);
            const float4 v1 = *(const float4*)(src + 4);
            const float4 v2 = *(const float4*)(src + 8);
            const float4 v3 = *(const float4*)(src + 12);
            u16x8 h0, h1;
            h0[0]=f2bf(v0.x); h0[1]=f2bf(v0.y); h0[2]=f2bf(v0.z); h0[3]=f2bf(v0.w);
            h0[4]=f2bf(v1.x); h0[5]=f2bf(v1.y); h0[6]=f2bf(v1.z); h0[7]=f2bf(v1.w);
            h1[0]=f2bf(v2.x); h1[1]=f2bf(v2.y); h1[2]=f2bf(v2.z); h1[3]=f2bf(v2.w);
            h1[4]=f2bf(v3.x); h1[5]=f2bf(v3.y); h1[6]=f2bf(v3.z); h1[7]=f2bf(v3.w);
            *(u16x8*)&DH[m*40 + k0]     = h0;
            *(u16x8*)&DH[m*40 + k0 + 8] = h1;
        }
        // stage W chunk [256 n][32 k] (bf16 copy)
        #pragma unroll
        for (int u = 0; u < 4; ++u) {
            const int nrow = (tid >> 2) + u * 64;
            const int ko   = (tid & 3) << 3;
            *(u16x8*)&WH[nrow*40 + ko] = *(const u16x8*)(WhP + (size_t)nrow * 768 + kc + ko);
        }
        __syncthreads();
        bf16x8 ah[2];
        #pragma unroll
        for (int ms = 0; ms < 2; ++ms)
            ah[ms] = *(bf16x8*)&DH[(w*32 + ms*16 + n15)*40 + quad*8];
        #pragma unroll
        for (int ns = 0; ns < 16; ++ns) {
            const bf16x8 bh = *(bf16x8*)&WH[(ns*16 + n15)*40 + quad*8];
            #pragma unroll
            for (int ms = 0; ms < 2; ++ms)
                acc[ms][ns] = MFMA16(ah[ms], bh, acc[ms][ns]);
        }
        __syncthreads();
    }

    float bv[16];
    #pragma unroll
    for (int ns = 0; ns < 16; ++ns) bv[ns] = bp[ns*16 + n15];

    // ---- row-major epilogue (Q half -> Qb; K half -> Kb) ----
    {
        ushort_t* dstRM = isQ ? Qb : Kb;
        #pragma unroll
        for (int hf = 0; hf < 2; ++hf) {
            __syncthreads();
            if ((w >> 1) == hf) {
                #pragma unroll
                for (int ms = 0; ms < 2; ++ms)
                    #pragma unroll
                    for (int ns = 0; ns < 16; ++ns)
                        #pragma unroll
                        for (int r = 0; r < 4; ++r) {
                            const int rl = (w & 1)*32 + ms*16 + quad*4 + r;
                            EP[rl*264 + ns*16 + n15] = f2bf(acc[ms][ns][r] + bv[ns]);
                        }
            }
            __syncthreads();
            const int row = tid >> 2;
            #pragma unroll
            for (int u = 0; u < 8; ++u) {
                const int co = (tid & 3)*8 + u*32;
                *(u16x8*)(dstRM + (drow + hf*64 + row)*256 + co) =
                    *(u16x8*)&EP[row*264 + co];
            }
        }
    }
    // ---- transposed epilogue (K half only): KTb[b][q][s] ----
    if (!isQ) {
        const int bidx = mtile >> 4;
        const int s0   = (mtile & 15) * 128;
        #pragma unroll
        for (int qh = 0; qh < 2; ++qh) {
            __syncthreads();
            #pragma unroll
            for (int ms = 0; ms < 2; ++ms)
                #pragma unroll
                for (int ns8 = 0; ns8 < 8; ++ns8) {
                    const int ns = qh*8 + ns8;
                    #pragma unroll
                    for (int r = 0; r < 4; ++r) {
                        const int rowm = w*32 + ms*16 + quad*4 + r;
                        EP[(ns8*16 + n15)*136 + rowm] = f2bf(acc[ms][ns][r] + bv[ns]);
                    }
                }
            __syncthreads();
            const int q = tid >> 1;
            #pragma unroll
            for (int u = 0; u < 8; ++u) {
                const int mo = (tid & 1)*8 + u*16;
                *(u16x8*)(KTb + ((size_t)(bidx*256 + qh*128 + q))*2048 + s0 + mo) =
                    *(u16x8*)&EP[q*136 + mo];
            }
        }
    }
}

// ---------------------------------------------------------------------------
// attn v6: flash attention, pure bf16 MFMA.
// Post-mortem v5: dbuf staged at loop TOP -> runtime-indexed buffers alias
// -> compiler can't hoist score ds_reads above staging ds_writes -> load
// latency serialized before every score phase (MfmaUtil 21->18).
// v6 = v2 math + T14 split on a SINGLE QS buffer, 2 barriers/jt:
//   top:  issue 8 Q(t+1) global loads -> REGISTERS qst (no LDS, no alias;
//         hoists above MFMAs; latency hides under scores+exp ~900 cyc)
//   scores(t) from QS; exp (+at2 KT loads); PS writes
//   B1    (all score QS-reads + PS writes complete)
//   ds_write qst -> QS  (v5 map: row=tid>>2, col=(tid&3)*8+u*32, XOR
//         (row&7)*8 -> 2-way bank overlap = free; overlaps PV MFMAs)
//   PV (PS reads, at2 regs)
//   B2    (QS writes done before next scores; PS reads done)
// Peak regs ~ xq128(acc) + kf64 + qst32 + sc32 + addr < 256: no spill.
// LDS 48.5KB; dconv/Db reverted (L3 working-set pollution, v5 FETCH+54%).
// ---------------------------------------------------------------------------
__global__ __launch_bounds__(256, 2) void attn_kernel(
    const ushort_t* __restrict__ Qb, const ushort_t* __restrict__ Kb,
    const ushort_t* __restrict__ KTb, float* __restrict__ pmax)
{
    __shared__ __align__(16) char smem[49664];
    ushort_t* QS = (ushort_t*)smem;                // [64 j][256 q] swizzled
    ushort_t* PS = (ushort_t*)(smem + 32768);      // [128 i][64 j] swizzled
    float*    l_lds = (float*)(smem + 49152);      // [128]

    const int tid  = threadIdx.x;
    const int w    = tid >> 6;
    const int quad = (tid >> 4) & 3;
    const int n15  = tid & 15;
    const int b    = blockIdx.x;
    const int it   = blockIdx.y;
    const int i0   = it * 128;

    const ushort_t* QbB  = Qb  + (size_t)b * Sn * QDn;
    const ushort_t* KbB  = Kb  + (size_t)b * Sn * QDn;
    const ushort_t* KTbB = KTb + (size_t)b * QDn * Sn;

    // staging geometry: row = tid>>2, cols (tid&3)*8 + u*32 (16B @ 64B
    // stride); 8-lane write group = 2 rows x 4 chunks, row-XOR -> 2-way free.
    const int sr  = tid >> 2;
    const int sc0 = (tid & 3) * 8;
    const int ssw = (sr & 7) * 8;
    const ushort_t* sQrow = QbB + (size_t)sr * QDn + sc0;
    ushort_t* sDrow = QS + sr * 256;

    f32x4 xq[4][8];                 // [qsub][isub], q = w*64+qs*16+quad*4+r, i = is*16+n15
    #pragma unroll
    for (int qs = 0; qs < 4; ++qs)
        #pragma unroll
        for (int is = 0; is < 8; ++is) xq[qs][is] = (f32x4)0.f;
    float l_i[2] = {0.f, 0.f};

    // ---- prologue: stage tile 0 (reg->LDS), load persistent K frags ----
    u16x8 qst[8];
    #pragma unroll
    for (int u = 0; u < 8; ++u) qst[u] = *(const u16x8*)(sQrow + u*32);
    #pragma unroll
    for (int u = 0; u < 8; ++u) *(u16x8*)&sDrow[(sc0 + u*32) ^ ssw] = qst[u];
    // kf[isub][ks]: B[n=i][k=q], i = i0 + w*32 + isub*16 + n15
    bf16x8 kf[2][8];
    #pragma unroll
    for (int isub = 0; isub < 2; ++isub) {
        const size_t irow = (size_t)(i0 + w*32 + isub*16 + n15) * QDn;
        #pragma unroll
        for (int ks = 0; ks < 8; ++ks)
            kf[isub][ks] = *(const bf16x8*)(KbB + irow + ks*32 + quad*8);
    }
    __syncthreads();

    const int swz = (n15 & 7) * 8;   // row-XOR for reads (shorts)

    for (int jt = 0; jt < Sn; jt += 64) {
        const bool pf = (jt + 64 < Sn);
        // ---- issue next-tile Q loads -> registers (latency hides under
        //      scores + exp; no LDS involvement, no alias hazard) ----
        if (pf) {
            const ushort_t* src = sQrow + (size_t)(jt + 64) * QDn;
            #pragma unroll
            for (int u = 0; u < 8; ++u) qst[u] = *(const u16x8*)(src + u*32);
        }
        // ---- scores: S^T[j][i], 8 k-steps from QS ----
        f32x4 sc[4][2];
        #pragma unroll
        for (int js = 0; js < 4; ++js) { sc[js][0] = (f32x4)0.f; sc[js][1] = (f32x4)0.f; }
        #pragma unroll
        for (int ks = 0; ks < 8; ++ks) {
            #pragma unroll
            for (int js = 0; js < 4; ++js) {
                const bf16x8 ah = *(bf16x8*)&QS[(js*16 + n15)*256 + ((ks*32 + quad*8) ^ swz)];
                sc[js][0] = MFMA16(ah, kf[0][ks], sc[js][0]);
                sc[js][1] = MFMA16(ah, kf[1][ks], sc[js][1]);
            }
        }
        // ---- exp (shift 0) + P write + l accumulate; at2 loads between
        //      the halves (sc[*][0] dead -> register headroom) ----
        bf16x8 at2[2][4];
        #pragma unroll
        for (int isub = 0; isub < 2; ++isub) {
            const int prow = (w*32 + isub*16 + n15) * 64;
            float rs = 0.f;
            #pragma unroll
            for (int js = 0; js < 4; ++js) {
                u16x4 ph;
                #pragma unroll
                for (int r = 0; r < 4; ++r) {
                    const float p = __expf(sc[js][isub][r] * 0.0625f);
                    rs += p;
                    ph[r] = f2bf(p);
                }
                *(u16x4*)&PS[prow + ((js*16 + quad*4) ^ swz)] = ph;
            }
            rs += __shfl_xor(rs, 16, 64);
            rs += __shfl_xor(rs, 32, 64);
            l_i[isub] += rs;
            if (isub == 0) {
                // at2[ks2][qs]: A[m=q][k=j], q = w*64+qs*16+n15, j = jt+ks2*32+quad*8+e
                #pragma unroll
                for (int ks2 = 0; ks2 < 2; ++ks2)
                    #pragma unroll
                    for (int qs = 0; qs < 4; ++qs)
                        at2[ks2][qs] = *(const bf16x8*)(
                            KTbB + (size_t)(w*64 + qs*16 + n15) * Sn + jt + ks2*32 + quad*8);
            }
        }
        __syncthreads();   // B1: score QS-reads + PS writes complete
        // ---- write staged Q(t+1) to QS (overlaps PV MFMAs) ----
        if (pf) {
            #pragma unroll
            for (int u = 0; u < 8; ++u)
                *(u16x8*)&sDrow[(sc0 + u*32) ^ ssw] = qst[u];
        }
        // ---- PV: A = at2 (registers), B = PS ----
        #pragma unroll
        for (int ks2 = 0; ks2 < 2; ++ks2) {
            #pragma unroll
            for (int is = 0; is < 8; ++is) {
                const bf16x8 pb = *(bf16x8*)&PS[(is*16 + n15)*64 + ((ks2*32 + quad*8) ^ swz)];
                #pragma unroll
                for (int qs = 0; qs < 4; ++qs)
                    xq[qs][is] = MFMA16(at2[ks2][qs], pb, xq[qs][is]);
            }
        }
        __syncthreads();   // B2: QS writes visible; PS reads done
    }

    // ---- epilogue: share l, normalize, max over block's 128 i ----
    if (quad == 0) {
        l_lds[w*32 + n15]      = l_i[0];
        l_lds[w*32 + 16 + n15] = l_i[1];
    }
    __syncthreads();
    float linv[8];
    #pragma unroll
    for (int is = 0; is < 8; ++is) linv[is] = 1.0f / l_lds[is*16 + n15];
    #pragma unroll
    for (int qs = 0; qs < 4; ++qs) {
        #pragma unroll
        for (int r = 0; r < 4; ++r) {
            float mv = xq[qs][0][r] * linv[0];
            #pragma unroll
            for (int is = 1; is < 8; ++is)
                mv = fmaxf(mv, xq[qs][is][r] * linv[is]);
            mv = fmaxf(mv, __shfl_xor(mv, 1, 64));
            mv = fmaxf(mv, __shfl_xor(mv, 2, 64));
            mv = fmaxf(mv, __shfl_xor(mv, 4, 64));
            mv = fmaxf(mv, __shfl_xor(mv, 8, 64));
            if (n15 == 0) {
                const int q = w*64 + qs*16 + quad*4 + r;
                pmax[((size_t)b * 16 + it) * QDn + q] = mv;
            }
        }
    }
}

// ---------------------------------------------------------------------------
// head: reduce 16 partial maxes, out = relu(xmax @ W3^T + b3). fp32.
// grid (32 b, 4 o-slices) = 128 blocks.
// ---------------------------------------------------------------------------
__global__ __launch_bounds__(256) void head_kernel(
    const float* __restrict__ pmax,
    const float* __restrict__ W3, const float* __restrict__ b3,
    float* __restrict__ out)
{
    __shared__ float xs[QDn];
    const int b = blockIdx.x, tid = threadIdx.x;
    float m = pmax[((size_t)b * 16) * QDn + tid];
    #pragma unroll
    for (int t = 1; t < 16; ++t)
        m = fmaxf(m, pmax[((size_t)b * 16 + t) * QDn + tid]);
    xs[tid] = m;
    __syncthreads();
    const int o = blockIdx.y * 256 + tid;
    const float4* wv = (const float4*)(W3 + (size_t)o * QDn);
    float s = 0.f;
    #pragma unroll 8
    for (int q4 = 0; q4 < QDn / 4; ++q4) {
        const float4 w4 = wv[q4];
        const float4 x4 = *(const float4*)&xs[q4 << 2];
        s += w4.x * x4.x + w4.y * x4.y + w4.z * x4.z + w4.w * x4.w;
    }
    out[(size_t)b * OUTn + o] = fmaxf(s + b3[o], 0.f);
}

// ---------------------------------------------------------------------------
extern "C" void kernel_launch(void* const* d_in, const int* in_sizes, int n_in,
                              void* d_out, int out_size, void* d_ws, size_t ws_size,
                              hipStream_t stream) {
    const float* data = (const float*)d_in[0];
    // d_in[1] = seq_len: unused by the reference computation
    const float* W1 = (const float*)d_in[2];
    const float* b1 = (const float*)d_in[3];
    const float* W2 = (const float*)d_in[4];
    const float* b2 = (const float*)d_in[5];
    const float* W3 = (const float*)d_in[6];
    const float* b3 = (const float*)d_in[7];
    float* out = (float*)d_out;

    // ws: Qb | Kb | KTb (each 16777216 bf16 = 32MB) | pmax 512KB | Wh 2x384KB
    ushort_t* Qb  = (ushort_t*)d_ws;
    ushort_t* Kb  = Qb  + 16777216;
    ushort_t* KTb = Kb  + 16777216;
    float*    pmax = (float*)((char*)d_ws + 100663296);
    ushort_t* W1h = (ushort_t*)((char*)d_ws + 100663296 + 524288);
    ushort_t* W2h = W1h + 196608;

    wconv_kernel<<<768, 256, 0, stream>>>(W1, W2, W1h, W2h);
    dim3 gP(2, 512);
    proj_kernel<<<gP, 256, 0, stream>>>(data, W1h, b1, W2h, b2, Qb, Kb, KTb);
    dim3 gA(Bn, 16);   // x = batch -> XCD = b%8: batch-pinned L2 locality
    attn_kernel<<<gA, 256, 0, stream>>>(Qb, Kb, KTb, pmax);
    dim3 gH(Bn, 4);
    head_kernel<<<gH, 256, 0, stream>>>(pmax, W3, b3, out);
}

// Round 7
// 662.231 us; speedup vs baseline: 1.3897x; 1.3897x over previous
//
#include <hip/hip_runtime.h>
#include <hip/hip_bf16.h>

#define Bn   32
#define Sn   2048
#define Dn   768
#define QDn  256
#define OUTn 1024

typedef __attribute__((ext_vector_type(8))) short          bf16x8;
typedef __attribute__((ext_vector_type(4))) float          f32x4;
typedef __attribute__((ext_vector_type(8))) unsigned short u16x8;
typedef __attribute__((ext_vector_type(4))) unsigned short u16x4;

typedef unsigned short ushort_t;

__device__ __forceinline__ unsigned short f2bf(float f) {
    unsigned int u = __float_as_uint(f);
    u = (u + 0x7FFFu + ((u >> 16) & 1u)) >> 16;   // RNE
    return (unsigned short)u;
}
#define MFMA16(a,b,c) __builtin_amdgcn_mfma_f32_16x16x32_bf16((a),(b),(c),0,0,0)

// ---------------------------------------------------------------------------
// wconv: one-time fp32 -> bf16 of W1/W2 (pure-bf16 pipeline: no lo terms).
// ---------------------------------------------------------------------------
__global__ __launch_bounds__(256) void wconv_kernel(
    const float* __restrict__ W1, const float* __restrict__ W2,
    ushort_t* __restrict__ W1h, ushort_t* __restrict__ W2h)
{
    const int idx = blockIdx.x * 256 + threadIdx.x;   // grid 768 -> 196608
    W1h[idx] = f2bf(W1[idx]);
    W2h[idx] = f2bf(W2[idx]);
}

// ---------------------------------------------------------------------------
// proj v2: [Q|K] = data @ W^T + b, pure bf16 MFMA.
// Wave decomposition reworked (2,16)->(8,4): wave owns 128m x 64n.
// Per kt per block: LDS b128 reads 72 -> 48 (ah 8 shared-rows + bh 4 per
// wave); bh single-use reads were the LDS-bound hot spot (~5:1 vs MFMA).
// acc[8][4] = 128 AGPRs (same budget).  Epilogues remapped, same output.
// grid (2 halves, 512 m-tiles), 256 thr = 4 waves, tile 128m x 256n.
// ---------------------------------------------------------------------------
__global__ __launch_bounds__(256, 2) void proj_kernel(
    const float* __restrict__ data,
    const ushort_t* __restrict__ W1h, const float* __restrict__ b1,
    const ushort_t* __restrict__ W2h, const float* __restrict__ b2,
    ushort_t* __restrict__ Qb, ushort_t* __restrict__ Kb,
    ushort_t* __restrict__ KTb)
{
    __shared__ __align__(16) char smem[34816];
    ushort_t* DH = (ushort_t*)smem;              // data bf16 [128][40]
    ushort_t* WH = (ushort_t*)(smem + 10240);    // W bf16 [256][40]
    ushort_t* EP = (ushort_t*)smem;              // epilogue overlay

    const int tid  = threadIdx.x;
    const int w    = tid >> 6;
    const int quad = (tid >> 4) & 3;
    const int n15  = tid & 15;
    const int mtile = blockIdx.y;
    const int half  = blockIdx.x;
    const bool isQ  = (half == 0);
    const ushort_t* WhP = isQ ? W1h : W2h;
    const float* bp = isQ ? b1 : b2;

    f32x4 acc[8][4];     // [ms][ns]: m = ms*16+quad*4+r, n = w*64+ns*16+n15
    #pragma unroll
    for (int i = 0; i < 8; ++i)
        #pragma unroll
        for (int j = 0; j < 4; ++j) acc[i][j] = (f32x4)0.f;

    const size_t drow = (size_t)mtile * 128;

    for (int kt = 0; kt < 24; ++kt) {
        const int kc = kt * 32;
        // stage data chunk [128 m][32 k] fp32 -> bf16
        {
            const int m  = tid >> 1;
            const int k0 = (tid & 1) << 4;
            const float* src = data + (drow + m) * 768 + kc + k0;
            const float4 v0 = *(const float4*)(src);
            const float4 v1 = *(const float4*)(src + 4);
            const float4 v2 = *(const float4*)(src + 8);
            const float4 v3 = *(const float4*)(src + 12);
            u16x8 h0, h1;
            h0[0]=f2bf(v0.x); h0[1]=f2bf(v0.y); h0[2]=f2bf(v0.z); h0[3]=f2bf(v0.w);
            h0[4]=f2bf(v1.x); h0[5]=f2bf(v1.y); h0[6]=f2bf(v1.z); h0[7]=f2bf(v1.w);
            h1[0]=f2bf(v2.x); h1[1]=f2bf(v2.y); h1[2]=f2bf(v2.z); h1[3]=f2bf(v2.w);
            h1[4]=f2bf(v3.x); h1[5]=f2bf(v3.y); h1[6]=f2bf(v3.z); h1[7]=f2bf(v3.w);
            *(u16x8*)&DH[m*40 + k0]     = h0;
            *(u16x8*)&DH[m*40 + k0 + 8] = h1;
        }
        // stage W chunk [256 n][32 k] (bf16 copy)
        #pragma unroll
        for (int u = 0; u < 4; ++u) {
            const int nrow = (tid >> 2) + u * 64;
            const int ko   = (tid & 3) << 3;
            *(u16x8*)&WH[nrow*40 + ko] = *(const u16x8*)(WhP + (size_t)nrow * 768 + kc + ko);
        }
        __syncthreads();
        bf16x8 ah[8], bh[4];
        #pragma unroll
        for (int ms = 0; ms < 8; ++ms)
            ah[ms] = *(bf16x8*)&DH[(ms*16 + n15)*40 + quad*8];
        #pragma unroll
        for (int ns = 0; ns < 4; ++ns)
            bh[ns] = *(bf16x8*)&WH[(w*64 + ns*16 + n15)*40 + quad*8];
        #pragma unroll
        for (int ns = 0; ns < 4; ++ns)
            #pragma unroll
            for (int ms = 0; ms < 8; ++ms)
                acc[ms][ns] = MFMA16(ah[ms], bh[ns], acc[ms][ns]);
        __syncthreads();
    }

    float bv[4];
    #pragma unroll
    for (int ns = 0; ns < 4; ++ns) bv[ns] = bp[w*64 + ns*16 + n15];

    // ---- row-major epilogue (Q half -> Qb; K half -> Kb) ----
    // hf half: rows hf*64..hf*64+63; ALL waves write their 64-n slice.
    {
        ushort_t* dstRM = isQ ? Qb : Kb;
        #pragma unroll
        for (int hf = 0; hf < 2; ++hf) {
            __syncthreads();
            #pragma unroll
            for (int ms2 = 0; ms2 < 4; ++ms2) {
                const int ms = hf*4 + ms2;
                #pragma unroll
                for (int ns = 0; ns < 4; ++ns)
                    #pragma unroll
                    for (int r = 0; r < 4; ++r) {
                        const int rl64 = ms2*16 + quad*4 + r;
                        EP[rl64*264 + w*64 + ns*16 + n15] = f2bf(acc[ms][ns][r] + bv[ns]);
                    }
            }
            __syncthreads();
            const int row = tid >> 2;
            #pragma unroll
            for (int u = 0; u < 8; ++u) {
                const int co = (tid & 3)*8 + u*32;
                *(u16x8*)(dstRM + (drow + hf*64 + row)*256 + co) =
                    *(u16x8*)&EP[row*264 + co];
            }
        }
    }
    // ---- transposed epilogue (K half only): KTb[b][q][s] ----
    // qh half: q(=n) qh*128..qh*128+127 held by waves (w>>1)==qh.
    if (!isQ) {
        const int bidx = mtile >> 4;
        const int s0   = (mtile & 15) * 128;
        #pragma unroll
        for (int qh = 0; qh < 2; ++qh) {
            __syncthreads();
            if ((w >> 1) == qh) {
                #pragma unroll
                for (int ns = 0; ns < 4; ++ns) {
                    const int qloc = (w & 1)*64 + ns*16 + n15;
                    #pragma unroll
                    for (int ms = 0; ms < 8; ++ms)
                        #pragma unroll
                        for (int r = 0; r < 4; ++r) {
                            const int m = ms*16 + quad*4 + r;
                            EP[qloc*136 + m] = f2bf(acc[ms][ns][r] + bv[ns]);
                        }
                }
            }
            __syncthreads();
            const int q = tid >> 1;
            #pragma unroll
            for (int u = 0; u < 8; ++u) {
                const int mo = (tid & 1)*8 + u*16;
                *(u16x8*)(KTb + ((size_t)(bidx*256 + qh*128 + q))*2048 + s0 + mo) =
                    *(u16x8*)&EP[q*136 + mo];
            }
        }
    }
}

// ---------------------------------------------------------------------------
// attn v7: v2 structure EXACTLY (verified 272us; register file saturated:
// 128 AGPR acc + ~128 arch -> any persistent addition spills, v6 lesson).
// Changes vs v2 (both register-neutral):
//  - staging map: row=tid>>2, col=(tid&3)*8+u*32, XOR (row&7)*8 -> write
//    groups hit 2-way bank overlap (free, m136) vs v2's 4-way.
//  - s_setprio(1) around score & PV MFMA clusters (T5): the two
//    co-resident independent blocks give the scheduler roles to arbitrate.
// 3 barriers/jt; QS single buffer; at2 after scores (v2 placement).
// ---------------------------------------------------------------------------
__global__ __launch_bounds__(256, 2) void attn_kernel(
    const ushort_t* __restrict__ Qb, const ushort_t* __restrict__ Kb,
    const ushort_t* __restrict__ KTb, float* __restrict__ pmax)
{
    __shared__ __align__(16) char smem[49664];
    ushort_t* QS = (ushort_t*)smem;                // [64 j][256 q] swizzled
    ushort_t* PS = (ushort_t*)(smem + 32768);      // [128 i][64 j] swizzled
    float*    l_lds = (float*)(smem + 49152);      // [128]

    const int tid  = threadIdx.x;
    const int w    = tid >> 6;
    const int quad = (tid >> 4) & 3;
    const int n15  = tid & 15;
    const int b    = blockIdx.x;
    const int it   = blockIdx.y;
    const int i0   = it * 128;

    const ushort_t* QbB  = Qb  + (size_t)b * Sn * QDn;
    const ushort_t* KbB  = Kb  + (size_t)b * Sn * QDn;
    const ushort_t* KTbB = KTb + (size_t)b * QDn * Sn;

    // staging geometry: row=tid>>2, cols (tid&3)*8 + u*32; 8-lane write
    // group = 2 rows x 4 slots -> 2-way bank overlap with row-XOR (free).
    const int sr  = tid >> 2;
    const int sc0 = (tid & 3) * 8;
    const int ssw = (sr & 7) * 8;
    const ushort_t* sQrow = QbB + (size_t)sr * QDn + sc0;
    ushort_t* sDrow = QS + sr * 256;

    // ---- persistent K_i B-frags, loaded DIRECT from row-major Kb ----
    bf16x8 kf[2][8];
    #pragma unroll
    for (int isub = 0; isub < 2; ++isub) {
        const size_t irow = (size_t)(i0 + w*32 + isub*16 + n15) * QDn;
        #pragma unroll
        for (int ks = 0; ks < 8; ++ks)
            kf[isub][ks] = *(const bf16x8*)(KbB + irow + ks*32 + quad*8);
    }

    f32x4 xq[4][8];                 // [qsub][isub]
    #pragma unroll
    for (int qs = 0; qs < 4; ++qs)
        #pragma unroll
        for (int is = 0; is < 8; ++is) xq[qs][is] = (f32x4)0.f;
    float l_i[2] = {0.f, 0.f};

    const int swz = (n15 & 7) * 8;   // row-XOR for reads (shorts)

    for (int jt = 0; jt < Sn; jt += 64) {
        __syncthreads();   // B0: prior PV PS-reads done; QS free
        // ---- stage Q tile [64 j][256 q], swizzled (2-way-free map) ----
        {
            const ushort_t* src = sQrow + (size_t)jt * QDn;
            #pragma unroll
            for (int u = 0; u < 8; ++u)
                *(u16x8*)&sDrow[(sc0 + u*32) ^ ssw] = *(const u16x8*)(src + u*32);
        }
        __syncthreads();   // B1: QS staged
        // ---- scores: S^T[j][i], 8 k-steps ----
        f32x4 sc[4][2];
        #pragma unroll
        for (int js = 0; js < 4; ++js) { sc[js][0] = (f32x4)0.f; sc[js][1] = (f32x4)0.f; }
        __builtin_amdgcn_s_setprio(1);
        #pragma unroll
        for (int ks = 0; ks < 8; ++ks) {
            #pragma unroll
            for (int js = 0; js < 4; ++js) {
                const bf16x8 ah = *(bf16x8*)&QS[(js*16 + n15)*256 + ((ks*32 + quad*8) ^ swz)];
                sc[js][0] = MFMA16(ah, kf[0][ks], sc[js][0]);
                sc[js][1] = MFMA16(ah, kf[1][ks], sc[js][1]);
            }
        }
        __builtin_amdgcn_s_setprio(0);
        // ---- PV A-frags direct from global KTb (L2-resident) ----
        bf16x8 at2[2][4];
        #pragma unroll
        for (int ks2 = 0; ks2 < 2; ++ks2)
            #pragma unroll
            for (int qs = 0; qs < 4; ++qs)
                at2[ks2][qs] = *(const bf16x8*)(
                    KTbB + (size_t)(w*64 + qs*16 + n15) * Sn + jt + ks2*32 + quad*8);
        // ---- exp (shift 0) + P write + l accumulate ----
        #pragma unroll
        for (int isub = 0; isub < 2; ++isub) {
            const int prow = (w*32 + isub*16 + n15) * 64;
            float rs = 0.f;
            #pragma unroll
            for (int js = 0; js < 4; ++js) {
                u16x4 ph;
                #pragma unroll
                for (int r = 0; r < 4; ++r) {
                    const float p = __expf(sc[js][isub][r] * 0.0625f);
                    rs += p;
                    ph[r] = f2bf(p);
                }
                *(u16x4*)&PS[prow + ((js*16 + quad*4) ^ swz)] = ph;
            }
            rs += __shfl_xor(rs, 16, 64);
            rs += __shfl_xor(rs, 32, 64);
            l_i[isub] += rs;
        }
        __syncthreads();   // B2: PS writes visible
        // ---- PV: A = at2 (registers), B = PS ----
        __builtin_amdgcn_s_setprio(1);
        #pragma unroll
        for (int ks2 = 0; ks2 < 2; ++ks2) {
            #pragma unroll
            for (int is = 0; is < 8; ++is) {
                const bf16x8 pb = *(bf16x8*)&PS[(is*16 + n15)*64 + ((ks2*32 + quad*8) ^ swz)];
                #pragma unroll
                for (int qs = 0; qs < 4; ++qs)
                    xq[qs][is] = MFMA16(at2[ks2][qs], pb, xq[qs][is]);
            }
        }
        __builtin_amdgcn_s_setprio(0);
    }

    // ---- epilogue: share l, normalize, max over block's 128 i ----
    __syncthreads();
    if (quad == 0) {
        l_lds[w*32 + n15]      = l_i[0];
        l_lds[w*32 + 16 + n15] = l_i[1];
    }
    __syncthreads();
    float linv[8];
    #pragma unroll
    for (int is = 0; is < 8; ++is) linv[is] = 1.0f / l_lds[is*16 + n15];
    #pragma unroll
    for (int qs = 0; qs < 4; ++qs) {
        #pragma unroll
        for (int r = 0; r < 4; ++r) {
            float mv = xq[qs][0][r] * linv[0];
            #pragma unroll
            for (int is = 1; is < 8; ++is)
                mv = fmaxf(mv, xq[qs][is][r] * linv[is]);
            mv = fmaxf(mv, __shfl_xor(mv, 1, 64));
            mv = fmaxf(mv, __shfl_xor(mv, 2, 64));
            mv = fmaxf(mv, __shfl_xor(mv, 4, 64));
            mv = fmaxf(mv, __shfl_xor(mv, 8, 64));
            if (n15 == 0) {
                const int q = w*64 + qs*16 + quad*4 + r;
                pmax[((size_t)b * 16 + it) * QDn + q] = mv;
            }
        }
    }
}

// ---------------------------------------------------------------------------
// head: reduce 16 partial maxes, out = relu(xmax @ W3^T + b3). fp32.
// grid (32 b, 4 o-slices) = 128 blocks.
// ---------------------------------------------------------------------------
__global__ __launch_bounds__(256) void head_kernel(
    const float* __restrict__ pmax,
    const float* __restrict__ W3, const float* __restrict__ b3,
    float* __restrict__ out)
{
    __shared__ float xs[QDn];
    const int b = blockIdx.x, tid = threadIdx.x;
    float m = pmax[((size_t)b * 16) * QDn + tid];
    #pragma unroll
    for (int t = 1; t < 16; ++t)
        m = fmaxf(m, pmax[((size_t)b * 16 + t) * QDn + tid]);
    xs[tid] = m;
    __syncthreads();
    const int o = blockIdx.y * 256 + tid;
    const float4* wv = (const float4*)(W3 + (size_t)o * QDn);
    float s = 0.f;
    #pragma unroll 8
    for (int q4 = 0; q4 < QDn / 4; ++q4) {
        const float4 w4 = wv[q4];
        const float4 x4 = *(const float4*)&xs[q4 << 2];
        s += w4.x * x4.x + w4.y * x4.y + w4.z * x4.z + w4.w * x4.w;
    }
    out[(size_t)b * OUTn + o] = fmaxf(s + b3[o], 0.f);
}

// ---------------------------------------------------------------------------
extern "C" void kernel_launch(void* const* d_in, const int* in_sizes, int n_in,
                              void* d_out, int out_size, void* d_ws, size_t ws_size,
                              hipStream_t stream) {
    const float* data = (const float*)d_in[0];
    // d_in[1] = seq_len: unused by the reference computation
    const float* W1 = (const float*)d_in[2];
    const float* b1 = (const float*)d_in[3];
    const float* W2 = (const float*)d_in[4];
    const float* b2 = (const float*)d_in[5];
    const float* W3 = (const float*)d_in[6];
    const float* b3 = (const float*)d_in[7];
    float* out = (float*)d_out;

    // ws: Qb | Kb | KTb (each 16777216 bf16 = 32MB) | pmax 512KB | Wh 2x384KB
    ushort_t* Qb  = (ushort_t*)d_ws;
    ushort_t* Kb  = Qb  + 16777216;
    ushort_t* KTb = Kb  + 16777216;
    float*    pmax = (float*)((char*)d_ws + 100663296);
    ushort_t* W1h = (ushort_t*)((char*)d_ws + 100663296 + 524288);
    ushort_t* W2h = W1h + 196608;

    wconv_kernel<<<768, 256, 0, stream>>>(W1, W2, W1h, W2h);
    dim3 gP(2, 512);
    proj_kernel<<<gP, 256, 0, stream>>>(data, W1h, b1, W2h, b2, Qb, Kb, KTb);
    dim3 gA(Bn, 16);   // x = batch -> XCD = b%8: batch-pinned L2 locality
    attn_kernel<<<gA, 256, 0, stream>>>(Qb, Kb, KTb, pmax);
    dim3 gH(Bn, 4);
    head_kernel<<<gH, 256, 0, stream>>>(pmax, W3, b3, out);
}